// Round 21
// baseline (190.437 us; speedup 1.0000x reference)
//
#include <hip/hip_runtime.h>

#define TSEQ 512
#define BSZN 4
#define NH 16
#define NBN 32
#define EMB 1024
#define HD 64
#define TGT 1536
#define MROWS 6144
#define LOG2E 1.44269504088896f

typedef unsigned short ushort_t;
typedef __bf16 bf8 __attribute__((ext_vector_type(8)));
typedef __bf16 bf2_t __attribute__((ext_vector_type(2)));
typedef ushort_t u16x8v __attribute__((ext_vector_type(8)));
typedef float f32x4 __attribute__((ext_vector_type(4)));

__device__ __forceinline__ unsigned short f2bf(float f) {
  return __builtin_bit_cast(unsigned short, (__bf16)f);
}

__device__ __forceinline__ float bf2f(unsigned short u) {
  return __builtin_bit_cast(float, (unsigned int)u << 16);
}

__device__ __forceinline__ unsigned int packbf(float a, float b) {
  bf2_t t;
  t[0] = (__bf16)a;
  t[1] = (__bf16)b;
  return __builtin_bit_cast(unsigned int, t);
}

__device__ __forceinline__ void gload16(const void* g, void* l) {
  __builtin_amdgcn_global_load_lds(
      (const __attribute__((address_space(1))) void*)g,
      (__attribute__((address_space(3))) void*)l, 16, 0, 0);
}

__device__ __forceinline__ f32x4 mfma_bf16(bf8 a, bf8 b, f32x4 c) {
  return __builtin_amdgcn_mfma_f32_16x16x32_bf16(a, b, c, 0, 0, 0);
}

__device__ __forceinline__ float lanebcast(float v, int srclane) {
  return __builtin_bit_cast(float,
      __builtin_amdgcn_ds_bpermute(srclane * 4, __builtin_bit_cast(int, v)));
}

// ---------------- fused prep: fp32->bf16 (4 segs) + combined mask|bucket ----------------
__global__ void prep_all_kernel(const float* __restrict__ q, const float* __restrict__ win,
                                const float* __restrict__ wout, const float* __restrict__ wrel,
                                const int* __restrict__ ibm, const int* __restrict__ ibr,
                                const float* __restrict__ mm, const float* __restrict__ mng,
                                ushort_t* __restrict__ qo, ushort_t* __restrict__ wino,
                                ushort_t* __restrict__ wouto, ushort_t* __restrict__ wrelo,
                                unsigned int* __restrict__ cm, unsigned int* __restrict__ cng) {
  const int i = blockIdx.x * blockDim.x + threadIdx.x;
  const int n0 = 1572864, n1 = 786432, n2 = 262144, n3 = 131072;
  const int ncvt = n0 + n1 + n2 + n3;
  const int nm = 262144, nr = 1048576;
  if (i < ncvt) {
    const float* src;
    ushort_t* dst;
    int off;
    if (i < n0) { src = q; dst = qo; off = i; }
    else if (i < n0 + n1) { src = win; dst = wino; off = i - n0; }
    else if (i < n0 + n1 + n2) { src = wout; dst = wouto; off = i - n0 - n1; }
    else { src = wrel; dst = wrelo; off = i - n0 - n1 - n2; }
    const float4 v = reinterpret_cast<const float4*>(src)[off];
    ushort4 o;
    o.x = f2bf(v.x); o.y = f2bf(v.y); o.z = f2bf(v.z); o.w = f2bf(v.w);
    reinterpret_cast<ushort4*>(dst)[off] = o;
  } else if (i < ncvt + nm) {
    const int f = (i - ncvt) * 4;
    const int4 ib = *reinterpret_cast<const int4*>(ibm + f);
    const float4 mk = *reinterpret_cast<const float4*>(mm + (f & 262143));
    uint4 o;
    o.x = ((unsigned int)f2bf(mk.x * LOG2E) << 16) | ((unsigned int)ib.x & 31u);
    o.y = ((unsigned int)f2bf(mk.y * LOG2E) << 16) | ((unsigned int)ib.y & 31u);
    o.z = ((unsigned int)f2bf(mk.z * LOG2E) << 16) | ((unsigned int)ib.z & 31u);
    o.w = ((unsigned int)f2bf(mk.w * LOG2E) << 16) | ((unsigned int)ib.w & 31u);
    *reinterpret_cast<uint4*>(cm + f) = o;
  } else if (i < ncvt + nm + nr) {
    const int f = (i - ncvt - nm) * 4;
    const int ib_off = ((f >> 20) << 19) + (f & 524287);
    const int mk_off = f & 1048575;
    const int4 ib = *reinterpret_cast<const int4*>(ibr + ib_off);
    const float4 mk = *reinterpret_cast<const float4*>(mng + mk_off);
    uint4 o;
    o.x = ((unsigned int)f2bf(mk.x * LOG2E) << 16) | ((unsigned int)ib.x & 31u);
    o.y = ((unsigned int)f2bf(mk.y * LOG2E) << 16) | ((unsigned int)ib.y & 31u);
    o.z = ((unsigned int)f2bf(mk.z * LOG2E) << 16) | ((unsigned int)ib.z & 31u);
    o.w = ((unsigned int)f2bf(mk.w * LOG2E) << 16) | ((unsigned int)ib.w & 31u);
    *reinterpret_cast<uint4*>(cng + f) = o;
  }
}

// ---------------- GEMM (in-proj + rel fused): BK=64, 3-buffer 2-deep prefetch ----------
// counted vmcnt(8): stage(t+2) issued before compute(t); never drain to 0 mid-loop.
// XCD-confined chunked dispatch. epilogues: bn<8 Q, 8..15 K, 16..23 Vt, >=24 VMh.
__global__ __launch_bounds__(256) void gemm_in(
    const ushort_t* __restrict__ A, const ushort_t* __restrict__ B,
    const float* __restrict__ bias,
    ushort_t* __restrict__ Qo, ushort_t* __restrict__ Ko, ushort_t* __restrict__ Vto,
    const ushort_t* __restrict__ B2, const float* __restrict__ bias2,
    ushort_t* __restrict__ VMo, int K) {
  __shared__ ushort_t lds[3][16384];   // per buf: lA 8192 | lB 8192 (u16)

  const int tid = threadIdx.x;
  const int lane = tid & 63;
  const int wid = tid >> 6;
  const int l15 = lane & 15, l4 = lane >> 4;

  int bm, bn;
  {
    const int n = blockIdx.x;
    const int xcd = n & 7;
    const int idx = n >> 3;
    const int chunk = idx / 42;
    const int w = idx - chunk * 42;
    bm = xcd * 6 + (w % 6);
    bn = chunk * 7 + (w / 6);
  }
  const int wm = (wid >> 1) * 64, wn = (wid & 1) * 64;
  const bool isrel = (bn >= 24);

  f32x4 acc[4][4] = {};

  const int r8 = tid >> 3;
  const int c8 = ((tid & 7) ^ (r8 & 7)) * 8;
  const ushort_t* Ag = A + (size_t)(bm * 128 + r8) * K + c8;
  const ushort_t* Bg = isrel ? B2 + (size_t)((bn - 24) * 128 + r8) * K + c8
                             : B + (size_t)(bn * 128 + r8) * K + c8;

  auto stage = [&](int kt, int bf) {
    ushort_t* lAp = lds[bf] + tid * 8;
    ushort_t* lBp = lds[bf] + 8192 + tid * 8;
#pragma unroll
    for (int i = 0; i < 4; ++i) {
      gload16(Ag + (size_t)i * 32 * K + kt, lAp + i * 2048);
      gload16(Bg + (size_t)i * 32 * K + kt, lBp + i * 2048);
    }
  };

  // prologue: 2 tiles in flight; wait for tile 0 only (8 newest stay outstanding)
  stage(0, 0);
  stage(64, 1);
  asm volatile("s_waitcnt vmcnt(8)" ::: "memory");
  __builtin_amdgcn_s_barrier();

  const int NT = K >> 6;
  for (int t = 0; t < NT; ++t) {
    if (t + 2 < NT) stage((t + 2) * 64, (t + 2) % 3);   // 2-deep prefetch
    const ushort_t* lA = lds[t % 3];
    const ushort_t* lB = lds[t % 3] + 8192;
#pragma unroll
    for (int k0 = 0; k0 < 2; ++k0) {
      bf8 af[4], bv[4];
#pragma unroll
      for (int mi = 0; mi < 4; ++mi) {
        const int row = wm + mi * 16 + l15;
        const int slot = (k0 * 4 + l4) ^ (row & 7);
        af[mi] = *reinterpret_cast<const bf8*>(lA + row * 64 + slot * 8);
      }
#pragma unroll
      for (int ni = 0; ni < 4; ++ni) {
        const int row = wn + ni * 16 + l15;
        const int slot = (k0 * 4 + l4) ^ (row & 7);
        bv[ni] = *reinterpret_cast<const bf8*>(lB + row * 64 + slot * 8);
      }
      __builtin_amdgcn_s_setprio(1);
#pragma unroll
      for (int mi = 0; mi < 4; ++mi)
#pragma unroll
        for (int ni = 0; ni < 4; ++ni)
          acc[mi][ni] = mfma_bf16(af[mi], bv[ni], acc[mi][ni]);
      __builtin_amdgcn_s_setprio(0);
    }
    // need stage(t+1) complete; leave stage(t+2)'s 8 loads in flight
    if (t + 2 < NT) {
      asm volatile("s_waitcnt vmcnt(8)" ::: "memory");
    } else if (t + 1 < NT) {
      asm volatile("s_waitcnt vmcnt(0)" ::: "memory");
    }
    __builtin_amdgcn_s_barrier();
  }

  if (bn < 16) {
    // ---- Q/K: transpose through LDS, store full 128B rows
    char* tb = reinterpret_cast<char*>(&lds[0][0]);   // [128 rows][256B], XOR (row&7)<<4
    const float scale = (bn < 8) ? (0.125f * LOG2E) : 1.f;
#pragma unroll
    for (int ni = 0; ni < 4; ++ni) {
      const int colloc = wn + ni * 16 + l15;
      const float bc = bias[bn * 128 + colloc];
#pragma unroll
      for (int mi = 0; mi < 4; ++mi) {
        f32x4 v = acc[mi][ni];
#pragma unroll
        for (int r = 0; r < 4; ++r) {
          const int row_loc = wm + mi * 16 + l4 * 4 + r;
          const int byteoff = row_loc * 256 + ((colloc * 2) ^ ((row_loc & 7) << 4));
          *reinterpret_cast<ushort_t*>(tb + byteoff) = f2bf((v[r] + bc) * scale);
        }
      }
    }
    __syncthreads();
    ushort_t* dst = (bn < 8) ? Qo : Ko;
    const int tglob0 = bm * 32;
#pragma unroll
    for (int p = 0; p < 2; ++p) {
      const int pair = wid * 2 + p;
      const int bb = pair >> 1;
      const int hl = pair & 1;
      const int h = (bn & 7) * 2 + hl;
      const int bh = bb * NH + h;
#pragma unroll
      for (int ii = 0; ii < 4; ++ii) {
        const int t_loc = ii * 8 + (lane >> 3);
        const int row_loc = t_loc * 4 + bb;
        const int byteoff = row_loc * 256 +
            ((hl * 128 + (lane & 7) * 16) ^ ((row_loc & 7) << 4));
        const u16x8v val = *reinterpret_cast<const u16x8v*>(tb + byteoff);
        *reinterpret_cast<u16x8v*>(
            dst + ((size_t)bh * TGT + tglob0 + t_loc) * HD + (lane & 7) * 8) = val;
      }
    }
    return;
  }

  if (bn < 24) {
    // ---- Vt part: transpose through LDS, store full 64B lines
    char* tb = reinterpret_cast<char*>(&lds[0][0]);
#pragma unroll
    for (int ni = 0; ni < 4; ++ni) {
      const int colloc = wn + ni * 16 + l15;
      const float bc = bias[bn * 128 + colloc];
      const unsigned int swz = (colloc & 7) << 4;
#pragma unroll
      for (int mi = 0; mi < 4; ++mi) {
        const int t_loc = (wm >> 2) + mi * 4 + l4;
        f32x4 v = acc[mi][ni];
#pragma unroll
        for (int r = 0; r < 4; ++r) {
          const int byteoff = colloc * 256 + ((r * 64 + t_loc * 2) ^ swz);
          *reinterpret_cast<ushort_t*>(tb + byteoff) = f2bf(v[r] + bc);
        }
      }
    }
    __syncthreads();
    const int tglob0 = bm * 32;
#pragma unroll
    for (int p = 0; p < 2; ++p) {
      const int pair = wid * 2 + p;
      const int bb = pair >> 1;
      const int hl = pair & 1;
      const int hh = (bn - 16) * 2 + hl;
      const int bh = bb * NH + hh;
      const int tch = lane & 3;
#pragma unroll
      for (int ii = 0; ii < 4; ++ii) {
        const int dloc = ii * 16 + (lane >> 2);
        const int colloc = hl * 64 + dloc;
        const int byteoff = colloc * 256 + ((bb * 64 + tch * 16) ^ ((colloc & 7) << 4));
        const u16x8v val = *reinterpret_cast<const u16x8v*>(tb + byteoff);
        *reinterpret_cast<u16x8v*>(
            Vto + ((size_t)bh * HD + dloc) * TGT + tglob0 + tch * 8) = val;
      }
    }
    return;
  }

  // ---- VMh epilogue (isrel)
#pragma unroll
  for (int ni = 0; ni < 4; ++ni) {
    const int colloc = wn + ni * 16 + l15;
    const int colrel = (bn - 24) * 128 + colloc;
    const float bc = bias2[colrel];
#pragma unroll
    for (int mi = 0; mi < 4; ++mi) {
      const int row0 = bm * 128 + wm + mi * 16 + l4 * 4;
      f32x4 v = acc[mi][ni];
#pragma unroll
      for (int r = 0; r < 4; ++r) {
        const int row = row0 + r;
        const float val = v[r] + bc;
        const int hh = colrel & 15, nb = colrel >> 4;
        const int qg = row >> 2, bb2 = row & 3;
        VMo[(((size_t)(bb2 * NH + hh)) * TGT + qg) * NBN + nb] = f2bf(val * LOG2E);
      }
    }
  }
}

// ---------------- out-projection: BM=64 x BN=128, 768 blocks, 48KB dbuf ----------------
__global__ __launch_bounds__(256) void gemm_out(
    const ushort_t* __restrict__ A, const ushort_t* __restrict__ B,
    const float* __restrict__ bias, float* __restrict__ Cf) {
  __shared__ ushort_t lds[2][12288];   // per buf: lA 4096 (64x64) | lB 8192 (128x64)
  const int K = 1024, N = 1024;
  const int tid = threadIdx.x;
  const int lane = tid & 63, wid = tid >> 6;
  const int l15 = lane & 15, l4 = lane >> 4;

  const int n = blockIdx.x;
  const int xcd = n & 7;
  const int idx = n >> 3;               // 0..95
  const int bm = xcd * 12 + (idx % 12); // 0..95
  const int bn = idx / 12;              // 0..7
  const int wm = (wid >> 1) * 32, wn = (wid & 1) * 64;

  f32x4 acc[2][4] = {};

  const int rr = tid >> 3;              // 0..31
  const int sl = tid & 7;
  const int cA = (sl ^ (rr & 7)) * 8;

  auto stage = [&](int kt, int bf) {
    ushort_t* base = lds[bf];
#pragma unroll
    for (int i = 0; i < 2; ++i) {
      const int row = rr + i * 32;
      gload16(A + (size_t)(bm * 64 + row) * K + cA + kt, base + tid * 8 + i * 2048);
    }
#pragma unroll
    for (int i = 0; i < 4; ++i) {
      const int row = rr + i * 32;
      gload16(B + (size_t)(bn * 128 + row) * K + cA + kt, base + 4096 + tid * 8 + i * 2048);
    }
  };

  stage(0, 0);
  asm volatile("s_waitcnt vmcnt(0)" ::: "memory");
  __builtin_amdgcn_s_barrier();

  const int NT = K >> 6;
  int cur = 0;
  for (int t = 0; t < NT; ++t) {
    if (t + 1 < NT) stage((t + 1) * 64, cur ^ 1);
    const ushort_t* lA = lds[cur];
    const ushort_t* lB = lds[cur] + 4096;
#pragma unroll
    for (int k0 = 0; k0 < 2; ++k0) {
      bf8 af[2], bv[4];
#pragma unroll
      for (int mi = 0; mi < 2; ++mi) {
        const int row = wm + mi * 16 + l15;
        const int slot = (k0 * 4 + l4) ^ (row & 7);
        af[mi] = *reinterpret_cast<const bf8*>(lA + row * 64 + slot * 8);
      }
#pragma unroll
      for (int ni = 0; ni < 4; ++ni) {
        const int row = wn + ni * 16 + l15;
        const int slot = (k0 * 4 + l4) ^ (row & 7);
        bv[ni] = *reinterpret_cast<const bf8*>(lB + row * 64 + slot * 8);
      }
      __builtin_amdgcn_s_setprio(1);
#pragma unroll
      for (int mi = 0; mi < 2; ++mi)
#pragma unroll
        for (int ni = 0; ni < 4; ++ni)
          acc[mi][ni] = mfma_bf16(af[mi], bv[ni], acc[mi][ni]);
      __builtin_amdgcn_s_setprio(0);
    }
    asm volatile("s_waitcnt vmcnt(0)" ::: "memory");
    __builtin_amdgcn_s_barrier();
    cur ^= 1;
  }

#pragma unroll
  for (int ni = 0; ni < 4; ++ni) {
    const int col = bn * 128 + wn + ni * 16 + l15;
    const float bc = bias[col];
#pragma unroll
    for (int mi = 0; mi < 2; ++mi) {
      const int row0 = bm * 64 + wm + mi * 16 + l4 * 4;
      f32x4 v = acc[mi][ni];
#pragma unroll
      for (int r = 0; r < 4; ++r)
        Cf[(size_t)(row0 + r) * N + col] = v[r] + bc;
    }
  }
}

// ---------------- fused attention: block = (b,h,z,128 q-rows), 4 waves x 32 rows ----------
// Fixed-reference exp2 softmax; per-lane l partials reduced in epilogue.
// 2-phase K/V dbuf; QK hoisted for both th; setprio on MFMA clusters.
__global__ __launch_bounds__(256, 3) void attn_kernel(
    const ushort_t* __restrict__ Q, const ushort_t* __restrict__ Kb,
    const ushort_t* __restrict__ Vt, const ushort_t* __restrict__ VMh,
    const unsigned int* __restrict__ comb_main, const unsigned int* __restrict__ comb_ng,
    ushort_t* __restrict__ AT) {
  __shared__ unsigned char kbuf[2][8192];
  __shared__ unsigned char vbuf[2][8192];
  __shared__ ushort_t vmt16[4][1088];      // per wave [32 t][34] bf16
  __shared__ unsigned int pbl[4][576];     // per wave [16 t][36 dw]

  const int tid = threadIdx.x;
  const int lane = tid & 63, wid = tid >> 6;
  const int l15 = lane & 15, l4 = lane >> 4;

  const int n = blockIdx.x;
  const int xcd = n & 7;
  const int b = xcd >> 1;
  const int idx = (xcd & 1) * 96 + (n >> 3);
  const int h = idx / 12;
  const int rem = idx - h * 12;
  const int z = rem >> 2;
  const int blk = rem & 3;
  const int g = (z == 0) ? 0 : z - 1;
  const int bh = b * NH + h;
  const int t0 = blk * 128 + wid * 32;
  const int qrow0 = (z == 0) ? t0 : TSEQ + g * TSEQ + t0;
  const int nsb = (z == 0) ? 8 : 16;

  {
    const ushort_t* src = VMh + ((size_t)bh * TGT + qrow0) * NBN;
    ushort_t* dst = vmt16[wid];
#pragma unroll
    for (int half = 0; half < 2; ++half) {
      const u16x8v v = *reinterpret_cast<const u16x8v*>(src + half * 512 + lane * 8);
      const int r = half * 16 + (lane >> 2);
      const int c0 = (lane & 3) * 8;
#pragma unroll
      for (int i = 0; i < 8; ++i) dst[r * 34 + c0 + i] = v[i];
    }
  }

  bf8 qf[2][2];
#pragma unroll
  for (int th = 0; th < 2; ++th)
#pragma unroll
    for (int hf = 0; hf < 2; ++hf)
      qf[th][hf] = *reinterpret_cast<const bf8*>(
          &Q[((size_t)bh * TGT + qrow0 + th * 16 + l15) * HD + hf * 32 + l4 * 8]);

  const unsigned int* cb[2];
  {
    const unsigned int* cbase = (z == 0)
        ? comb_main + (size_t)b * TSEQ * TSEQ
        : comb_ng + (size_t)(b * 2 + g) * TSEQ * (2 * TSEQ);
    const int sstr = (z == 0) ? TSEQ : 2 * TSEQ;
    cb[0] = cbase + (size_t)(t0 + l15) * sstr;
    cb[1] = cbase + (size_t)(t0 + 16 + l15) * sstr;
  }

  float l_run[2] = {0.f, 0.f};
  f32x4 oacc[2][4] = {};

  const int r8 = lane >> 3;
  const int swzs = ((lane & 7) ^ r8) << 4;
  const int swzr = (l15 & 7) << 4;

  auto stage = [&](int sb, int bf) {
    const int srow0 = (sb < 8) ? sb * 64 : TSEQ + g * TSEQ + (sb - 8) * 64;
    const ushort_t* ks = Kb + ((size_t)bh * TGT + srow0 + wid * 16 + r8) * HD + (swzs >> 1);
    gload16(ks, &kbuf[bf][wid * 2048 + lane * 16]);
    gload16(ks + 8 * HD, &kbuf[bf][wid * 2048 + 1024 + lane * 16]);
    const ushort_t* vs = Vt + ((size_t)bh * HD + wid * 16 + r8) * TGT + srow0 + (swzs >> 1);
    gload16(vs, &vbuf[bf][wid * 2048 + lane * 16]);
    gload16(vs + 8 * TGT, &vbuf[bf][wid * 2048 + 1024 + lane * 16]);
  };

  stage(0, 0);
  asm volatile("s_waitcnt vmcnt(0)" ::: "memory");
  __builtin_amdgcn_s_barrier();

  int cur = 0;
  for (int sb = 0; sb < nsb; ++sb) {
    const int scol = sb * 64;
    if (sb + 1 < nsb) stage(sb + 1, cur ^ 1);

    const unsigned char* kb = kbuf[cur];
    const unsigned char* vbb = vbuf[cur];

    uint4 cw[2][4];
#pragma unroll
    for (int th = 0; th < 2; ++th) {
      const unsigned int* cwp = cb[th] + scol + l4 * 4;
      cw[th][0] = *reinterpret_cast<const uint4*>(cwp);
      cw[th][1] = *reinterpret_cast<const uint4*>(cwp + 16);
      cw[th][2] = *reinterpret_cast<const uint4*>(cwp + 32);
      cw[th][3] = *reinterpret_cast<const uint4*>(cwp + 48);
    }

    bf8 kf[4][2];
#pragma unroll
    for (int j = 0; j < 4; ++j) {
      const int row = j * 16 + l15;
      kf[j][0] = *reinterpret_cast<const bf8*>(kb + row * 128 + ((l4 * 16) ^ swzr));
      kf[j][1] = *reinterpret_cast<const bf8*>(kb + row * 128 + ((64 + l4 * 16) ^ swzr));
    }
    f32x4 st[2][4];
    __builtin_amdgcn_s_setprio(1);
#pragma unroll
    for (int th = 0; th < 2; ++th)
#pragma unroll
      for (int j = 0; j < 4; ++j) {
        f32x4 s4 = {};
        s4 = mfma_bf16(kf[j][0], qf[th][0], s4);
        s4 = mfma_bf16(kf[j][1], qf[th][1], s4);
        st[th][j] = s4;
      }
    __builtin_amdgcn_s_setprio(0);

#pragma unroll
    for (int th = 0; th < 2; ++th) {
      const ushort_t* vrow = vmt16[wid] + (th * 16 + l15) * 34;
      unsigned int pk[4][2];
      float lsum = 0.f;
#pragma unroll
      for (int j = 0; j < 4; ++j) {
        const unsigned int w0 = cw[th][j].x, w1 = cw[th][j].y;
        const unsigned int w2 = cw[th][j].z, w3 = cw[th][j].w;
        const float p0 = exp2f(st[th][j][0] + __builtin_bit_cast(float, w0 & 0xffff0000u) + bf2f(vrow[w0 & 31u]));
        const float p1 = exp2f(st[th][j][1] + __builtin_bit_cast(float, w1 & 0xffff0000u) + bf2f(vrow[w1 & 31u]));
        const float p2 = exp2f(st[th][j][2] + __builtin_bit_cast(float, w2 & 0xffff0000u) + bf2f(vrow[w2 & 31u]));
        const float p3 = exp2f(st[th][j][3] + __builtin_bit_cast(float, w3 & 0xffff0000u) + bf2f(vrow[w3 & 31u]));
        lsum += (p0 + p1) + (p2 + p3);
        pk[j][0] = packbf(p0, p1);
        pk[j][1] = packbf(p2, p3);
      }
      l_run[th] += lsum;

      {
        unsigned int* prow = &pbl[wid][l15 * 36];
#pragma unroll
        for (int j = 0; j < 4; ++j) {
          uint2 w2v;
          w2v.x = pk[j][0];
          w2v.y = pk[j][1];
          *reinterpret_cast<uint2*>(&prow[j * 8 + l4 * 2]) = w2v;
        }
      }
      const unsigned char* pbase = reinterpret_cast<const unsigned char*>(&pbl[wid][0]);
#pragma unroll
      for (int k32 = 0; k32 < 2; ++k32) {
        const bf8 pa = *reinterpret_cast<const bf8*>(
            pbase + l15 * 144 + k32 * 64 + l4 * 16);
        __builtin_amdgcn_s_setprio(1);
#pragma unroll
        for (int dt = 0; dt < 4; ++dt) {
          const bf8 vb = *reinterpret_cast<const bf8*>(
              vbb + (dt * 16 + l15) * 128 + ((k32 * 64 + l4 * 16) ^ swzr));
          oacc[th][dt] = mfma_bf16(pa, vb, oacc[th][dt]);
        }
        __builtin_amdgcn_s_setprio(0);
      }
    }

    asm volatile("s_waitcnt vmcnt(0)" ::: "memory");
    __builtin_amdgcn_s_barrier();
    cur ^= 1;
  }

  // ---- epilogue: deferred cross-lane l reduction, then divide + store
#pragma unroll
  for (int th = 0; th < 2; ++th) {
    float lt = l_run[th];
    lt += __shfl_xor(lt, 16);
    lt += __shfl_xor(lt, 32);
    const float linv = 1.f / lt;
    f32x4 bs;
    bs[0] = lanebcast(linv, l4 * 4 + 0);
    bs[1] = lanebcast(linv, l4 * 4 + 1);
    bs[2] = lanebcast(linv, l4 * 4 + 2);
    bs[3] = lanebcast(linv, l4 * 4 + 3);
#pragma unroll
    for (int dt = 0; dt < 4; ++dt) {
#pragma unroll
      for (int r = 0; r < 4; ++r) {
        const int tout = qrow0 + th * 16 + l4 * 4 + r;
        AT[((size_t)tout * BSZN + b) * EMB + h * HD + dt * 16 + l15] =
            f2bf(oacc[th][dt][r] * bs[r]);
      }
    }
  }
}

extern "C" void kernel_launch(void* const* d_in, const int* in_sizes, int n_in,
                              void* d_out, int out_size, void* d_ws, size_t ws_size,
                              hipStream_t stream) {
  const float* query     = (const float*)d_in[0];
  const float* mask_main = (const float*)d_in[1];
  const float* mask_ng   = (const float*)d_in[2];
  const int*   ib_main   = (const int*)d_in[3];
  const int*   ib_rel    = (const int*)d_in[4];
  const float* w_in      = (const float*)d_in[5];
  const float* b_in      = (const float*)d_in[6];
  const float* w_out     = (const float*)d_in[7];
  const float* b_out     = (const float*)d_in[8];
  const float* w_rel     = (const float*)d_in[9];
  const float* b_rel     = (const float*)d_in[10];
  float* out = (float*)d_out;

  ushort_t* qbf    = (ushort_t*)d_ws;            // 6291456
  ushort_t* winbf  = qbf + 6291456;              // 3145728
  ushort_t* woutbf = winbf + 3145728;            // 1048576
  ushort_t* relwbf = woutbf + 1048576;           // 524288
  ushort_t* Qb     = relwbf + 524288;            // 6291456
  ushort_t* Kbuf   = Qb + 6291456;               // 6291456
  ushort_t* Vtb    = Kbuf + 6291456;             // 6291456
  ushort_t* VMh    = Vtb + 6291456;              // 3145728
  unsigned int* comb_main = (unsigned int*)(VMh + 3145728);  // 1048576 u32
  unsigned int* comb_ng   = comb_main + 1048576;             // 4194304 u32
  ushort_t* AT     = qbf;                        // alias

  // fused prep: cvt + comb (mask pre-scaled by log2e)
  {
    const int total = 2752512 + 262144 + 1048576;
    prep_all_kernel<<<(total + 255) / 256, 256, 0, stream>>>(
        query, w_in, w_out, w_rel, ib_main, ib_rel, mask_main, mask_ng,
        qbf, winbf, woutbf, relwbf, comb_main, comb_ng);
  }

  // fused in-projection + rel-value table (XCD-confined, 3-buffer 2-deep prefetch)
  gemm_in<<<1344, 256, 0, stream>>>(qbf, winbf, b_in,
                                    Qb, Kbuf, Vtb, relwbf, b_rel, VMh, 1024);
  // fused attention
  attn_kernel<<<768, 256, 0, stream>>>(Qb, Kbuf, Vtb, VMh, comb_main, comb_ng, AT);
  // out-projection (BM=64, 768 blocks, 48KB dbuf -> 3 blocks/CU)
  gemm_out<<<768, 256, 0, stream>>>(AT, woutbf, b_out, out);
}

// Round 22
// 183.630 us; speedup vs baseline: 1.0371x; 1.0371x over previous
//
#include <hip/hip_runtime.h>

#define TSEQ 512
#define BSZN 4
#define NH 16
#define NBN 32
#define EMB 1024
#define HD 64
#define TGT 1536
#define MROWS 6144
#define LOG2E 1.44269504088896f

typedef unsigned short ushort_t;
typedef __bf16 bf8 __attribute__((ext_vector_type(8)));
typedef __bf16 bf2_t __attribute__((ext_vector_type(2)));
typedef ushort_t u16x8v __attribute__((ext_vector_type(8)));
typedef float f32x4 __attribute__((ext_vector_type(4)));

__device__ __forceinline__ unsigned short f2bf(float f) {
  return __builtin_bit_cast(unsigned short, (__bf16)f);
}

__device__ __forceinline__ float bf2f(unsigned short u) {
  return __builtin_bit_cast(float, (unsigned int)u << 16);
}

__device__ __forceinline__ unsigned int packbf(float a, float b) {
  bf2_t t;
  t[0] = (__bf16)a;
  t[1] = (__bf16)b;
  return __builtin_bit_cast(unsigned int, t);
}

__device__ __forceinline__ void gload16(const void* g, void* l) {
  __builtin_amdgcn_global_load_lds(
      (const __attribute__((address_space(1))) void*)g,
      (__attribute__((address_space(3))) void*)l, 16, 0, 0);
}

__device__ __forceinline__ f32x4 mfma_bf16(bf8 a, bf8 b, f32x4 c) {
  return __builtin_amdgcn_mfma_f32_16x16x32_bf16(a, b, c, 0, 0, 0);
}

__device__ __forceinline__ float lanebcast(float v, int srclane) {
  return __builtin_bit_cast(float,
      __builtin_amdgcn_ds_bpermute(srclane * 4, __builtin_bit_cast(int, v)));
}

// ---------------- fused prep: fp32->bf16 (4 segs) + combined mask|bucket ----------------
__global__ void prep_all_kernel(const float* __restrict__ q, const float* __restrict__ win,
                                const float* __restrict__ wout, const float* __restrict__ wrel,
                                const int* __restrict__ ibm, const int* __restrict__ ibr,
                                const float* __restrict__ mm, const float* __restrict__ mng,
                                ushort_t* __restrict__ qo, ushort_t* __restrict__ wino,
                                ushort_t* __restrict__ wouto, ushort_t* __restrict__ wrelo,
                                unsigned int* __restrict__ cm, unsigned int* __restrict__ cng) {
  const int i = blockIdx.x * blockDim.x + threadIdx.x;
  const int n0 = 1572864, n1 = 786432, n2 = 262144, n3 = 131072;
  const int ncvt = n0 + n1 + n2 + n3;
  const int nm = 262144, nr = 1048576;
  if (i < ncvt) {
    const float* src;
    ushort_t* dst;
    int off;
    if (i < n0) { src = q; dst = qo; off = i; }
    else if (i < n0 + n1) { src = win; dst = wino; off = i - n0; }
    else if (i < n0 + n1 + n2) { src = wout; dst = wouto; off = i - n0 - n1; }
    else { src = wrel; dst = wrelo; off = i - n0 - n1 - n2; }
    const float4 v = reinterpret_cast<const float4*>(src)[off];
    ushort4 o;
    o.x = f2bf(v.x); o.y = f2bf(v.y); o.z = f2bf(v.z); o.w = f2bf(v.w);
    reinterpret_cast<ushort4*>(dst)[off] = o;
  } else if (i < ncvt + nm) {
    const int f = (i - ncvt) * 4;
    const int4 ib = *reinterpret_cast<const int4*>(ibm + f);
    const float4 mk = *reinterpret_cast<const float4*>(mm + (f & 262143));
    uint4 o;
    o.x = ((unsigned int)f2bf(mk.x * LOG2E) << 16) | ((unsigned int)ib.x & 31u);
    o.y = ((unsigned int)f2bf(mk.y * LOG2E) << 16) | ((unsigned int)ib.y & 31u);
    o.z = ((unsigned int)f2bf(mk.z * LOG2E) << 16) | ((unsigned int)ib.z & 31u);
    o.w = ((unsigned int)f2bf(mk.w * LOG2E) << 16) | ((unsigned int)ib.w & 31u);
    *reinterpret_cast<uint4*>(cm + f) = o;
  } else if (i < ncvt + nm + nr) {
    const int f = (i - ncvt - nm) * 4;
    const int ib_off = ((f >> 20) << 19) + (f & 524287);
    const int mk_off = f & 1048575;
    const int4 ib = *reinterpret_cast<const int4*>(ibr + ib_off);
    const float4 mk = *reinterpret_cast<const float4*>(mng + mk_off);
    uint4 o;
    o.x = ((unsigned int)f2bf(mk.x * LOG2E) << 16) | ((unsigned int)ib.x & 31u);
    o.y = ((unsigned int)f2bf(mk.y * LOG2E) << 16) | ((unsigned int)ib.y & 31u);
    o.z = ((unsigned int)f2bf(mk.z * LOG2E) << 16) | ((unsigned int)ib.z & 31u);
    o.w = ((unsigned int)f2bf(mk.w * LOG2E) << 16) | ((unsigned int)ib.w & 31u);
    *reinterpret_cast<uint4*>(cng + f) = o;
  }
}

// ---------------- GEMM (in-proj + rel fused): BK=64 dbuf, XOR swizzle, XCD-confined ----
// epilogues: bn<8 Q, 8..15 K (LDS transpose), 16..23 Vt, >=24 VMh.
__global__ __launch_bounds__(256) void gemm_in(
    const ushort_t* __restrict__ A, const ushort_t* __restrict__ B,
    const float* __restrict__ bias,
    ushort_t* __restrict__ Qo, ushort_t* __restrict__ Ko, ushort_t* __restrict__ Vto,
    const ushort_t* __restrict__ B2, const float* __restrict__ bias2,
    ushort_t* __restrict__ VMo, int K) {
  __shared__ ushort_t lds[2][16384];   // per buf: lA 8192 | lB 8192 (u16)

  const int tid = threadIdx.x;
  const int lane = tid & 63;
  const int wid = tid >> 6;
  const int l15 = lane & 15, l4 = lane >> 4;

  int bm, bn;
  {
    const int n = blockIdx.x;
    const int xcd = n & 7;
    const int idx = n >> 3;
    const int chunk = idx / 42;
    const int w = idx - chunk * 42;
    bm = xcd * 6 + (w % 6);
    bn = chunk * 7 + (w / 6);
  }
  const int wm = (wid >> 1) * 64, wn = (wid & 1) * 64;
  const bool isrel = (bn >= 24);

  f32x4 acc[4][4] = {};

  const int r8 = tid >> 3;
  const int c8 = ((tid & 7) ^ (r8 & 7)) * 8;
  const ushort_t* Ag = A + (size_t)(bm * 128 + r8) * K + c8;
  const ushort_t* Bg = isrel ? B2 + (size_t)((bn - 24) * 128 + r8) * K + c8
                             : B + (size_t)(bn * 128 + r8) * K + c8;

  auto stage = [&](int kt, int bf) {
    ushort_t* lAp = lds[bf] + tid * 8;
    ushort_t* lBp = lds[bf] + 8192 + tid * 8;
#pragma unroll
    for (int i = 0; i < 4; ++i) {
      gload16(Ag + (size_t)i * 32 * K + kt, lAp + i * 2048);
      gload16(Bg + (size_t)i * 32 * K + kt, lBp + i * 2048);
    }
  };

  stage(0, 0);
  asm volatile("s_waitcnt vmcnt(0)" ::: "memory");
  __builtin_amdgcn_s_barrier();

  const int NT = K >> 6;
  int cur = 0;
  for (int t = 0; t < NT; ++t) {
    if (t + 1 < NT) stage((t + 1) * 64, cur ^ 1);   // prefetch flies under compute
    const ushort_t* lA = lds[cur];
    const ushort_t* lB = lds[cur] + 8192;
#pragma unroll
    for (int k0 = 0; k0 < 2; ++k0) {
      bf8 af[4], bv[4];
#pragma unroll
      for (int mi = 0; mi < 4; ++mi) {
        const int row = wm + mi * 16 + l15;
        const int slot = (k0 * 4 + l4) ^ (row & 7);
        af[mi] = *reinterpret_cast<const bf8*>(lA + row * 64 + slot * 8);
      }
#pragma unroll
      for (int ni = 0; ni < 4; ++ni) {
        const int row = wn + ni * 16 + l15;
        const int slot = (k0 * 4 + l4) ^ (row & 7);
        bv[ni] = *reinterpret_cast<const bf8*>(lB + row * 64 + slot * 8);
      }
      __builtin_amdgcn_s_setprio(1);
#pragma unroll
      for (int mi = 0; mi < 4; ++mi)
#pragma unroll
        for (int ni = 0; ni < 4; ++ni)
          acc[mi][ni] = mfma_bf16(af[mi], bv[ni], acc[mi][ni]);
      __builtin_amdgcn_s_setprio(0);
    }
    asm volatile("s_waitcnt vmcnt(0)" ::: "memory");
    __builtin_amdgcn_s_barrier();
    cur ^= 1;
  }

  if (bn < 16) {
    // ---- Q/K: transpose through LDS, store full 128B rows
    char* tb = reinterpret_cast<char*>(&lds[0][0]);   // [128 rows][256B], XOR (row&7)<<4
    const float scale = (bn < 8) ? (0.125f * LOG2E) : 1.f;
#pragma unroll
    for (int ni = 0; ni < 4; ++ni) {
      const int colloc = wn + ni * 16 + l15;
      const float bc = bias[bn * 128 + colloc];
#pragma unroll
      for (int mi = 0; mi < 4; ++mi) {
        f32x4 v = acc[mi][ni];
#pragma unroll
        for (int r = 0; r < 4; ++r) {
          const int row_loc = wm + mi * 16 + l4 * 4 + r;
          const int byteoff = row_loc * 256 + ((colloc * 2) ^ ((row_loc & 7) << 4));
          *reinterpret_cast<ushort_t*>(tb + byteoff) = f2bf((v[r] + bc) * scale);
        }
      }
    }
    __syncthreads();
    ushort_t* dst = (bn < 8) ? Qo : Ko;
    const int tglob0 = bm * 32;
#pragma unroll
    for (int p = 0; p < 2; ++p) {
      const int pair = wid * 2 + p;
      const int bb = pair >> 1;
      const int hl = pair & 1;
      const int h = (bn & 7) * 2 + hl;
      const int bh = bb * NH + h;
#pragma unroll
      for (int ii = 0; ii < 4; ++ii) {
        const int t_loc = ii * 8 + (lane >> 3);
        const int row_loc = t_loc * 4 + bb;
        const int byteoff = row_loc * 256 +
            ((hl * 128 + (lane & 7) * 16) ^ ((row_loc & 7) << 4));
        const u16x8v val = *reinterpret_cast<const u16x8v*>(tb + byteoff);
        *reinterpret_cast<u16x8v*>(
            dst + ((size_t)bh * TGT + tglob0 + t_loc) * HD + (lane & 7) * 8) = val;
      }
    }
    return;
  }

  if (bn < 24) {
    // ---- Vt part: transpose through LDS, store full 64B lines
    char* tb = reinterpret_cast<char*>(&lds[0][0]);
#pragma unroll
    for (int ni = 0; ni < 4; ++ni) {
      const int colloc = wn + ni * 16 + l15;
      const float bc = bias[bn * 128 + colloc];
      const unsigned int swz = (colloc & 7) << 4;
#pragma unroll
      for (int mi = 0; mi < 4; ++mi) {
        const int t_loc = (wm >> 2) + mi * 4 + l4;
        f32x4 v = acc[mi][ni];
#pragma unroll
        for (int r = 0; r < 4; ++r) {
          const int byteoff = colloc * 256 + ((r * 64 + t_loc * 2) ^ swz);
          *reinterpret_cast<ushort_t*>(tb + byteoff) = f2bf(v[r] + bc);
        }
      }
    }
    __syncthreads();
    const int tglob0 = bm * 32;
#pragma unroll
    for (int p = 0; p < 2; ++p) {
      const int pair = wid * 2 + p;
      const int bb = pair >> 1;
      const int hl = pair & 1;
      const int hh = (bn - 16) * 2 + hl;
      const int bh = bb * NH + hh;
      const int tch = lane & 3;
#pragma unroll
      for (int ii = 0; ii < 4; ++ii) {
        const int dloc = ii * 16 + (lane >> 2);
        const int colloc = hl * 64 + dloc;
        const int byteoff = colloc * 256 + ((bb * 64 + tch * 16) ^ ((colloc & 7) << 4));
        const u16x8v val = *reinterpret_cast<const u16x8v*>(tb + byteoff);
        *reinterpret_cast<u16x8v*>(
            Vto + ((size_t)bh * HD + dloc) * TGT + tglob0 + tch * 8) = val;
      }
    }
    return;
  }

  // ---- VMh epilogue (isrel)
#pragma unroll
  for (int ni = 0; ni < 4; ++ni) {
    const int colloc = wn + ni * 16 + l15;
    const int colrel = (bn - 24) * 128 + colloc;
    const float bc = bias2[colrel];
#pragma unroll
    for (int mi = 0; mi < 4; ++mi) {
      const int row0 = bm * 128 + wm + mi * 16 + l4 * 4;
      f32x4 v = acc[mi][ni];
#pragma unroll
      for (int r = 0; r < 4; ++r) {
        const int row = row0 + r;
        const float val = v[r] + bc;
        const int hh = colrel & 15, nb = colrel >> 4;
        const int qg = row >> 2, bb2 = row & 3;
        VMo[(((size_t)(bb2 * NH + hh)) * TGT + qg) * NBN + nb] = f2bf(val * LOG2E);
      }
    }
  }
}

// ---------------- out-projection: BM=64 x BN=128, 768 blocks, 48KB dbuf ----------------
__global__ __launch_bounds__(256) void gemm_out(
    const ushort_t* __restrict__ A, const ushort_t* __restrict__ B,
    const float* __restrict__ bias, float* __restrict__ Cf) {
  __shared__ ushort_t lds[2][12288];   // per buf: lA 4096 (64x64) | lB 8192 (128x64)
  const int K = 1024, N = 1024;
  const int tid = threadIdx.x;
  const int lane = tid & 63, wid = tid >> 6;
  const int l15 = lane & 15, l4 = lane >> 4;

  const int n = blockIdx.x;
  const int xcd = n & 7;
  const int idx = n >> 3;               // 0..95
  const int bm = xcd * 12 + (idx % 12); // 0..95
  const int bn = idx / 12;              // 0..7
  const int wm = (wid >> 1) * 32, wn = (wid & 1) * 64;

  f32x4 acc[2][4] = {};

  const int rr = tid >> 3;              // 0..31
  const int sl = tid & 7;
  const int cA = (sl ^ (rr & 7)) * 8;

  auto stage = [&](int kt, int bf) {
    ushort_t* base = lds[bf];
#pragma unroll
    for (int i = 0; i < 2; ++i) {
      const int row = rr + i * 32;
      gload16(A + (size_t)(bm * 64 + row) * K + cA + kt, base + tid * 8 + i * 2048);
    }
#pragma unroll
    for (int i = 0; i < 4; ++i) {
      const int row = rr + i * 32;
      gload16(B + (size_t)(bn * 128 + row) * K + cA + kt, base + 4096 + tid * 8 + i * 2048);
    }
  };

  stage(0, 0);
  asm volatile("s_waitcnt vmcnt(0)" ::: "memory");
  __builtin_amdgcn_s_barrier();

  const int NT = K >> 6;
  int cur = 0;
  for (int t = 0; t < NT; ++t) {
    if (t + 1 < NT) stage((t + 1) * 64, cur ^ 1);
    const ushort_t* lA = lds[cur];
    const ushort_t* lB = lds[cur] + 4096;
#pragma unroll
    for (int k0 = 0; k0 < 2; ++k0) {
      bf8 af[2], bv[4];
#pragma unroll
      for (int mi = 0; mi < 2; ++mi) {
        const int row = wm + mi * 16 + l15;
        const int slot = (k0 * 4 + l4) ^ (row & 7);
        af[mi] = *reinterpret_cast<const bf8*>(lA + row * 64 + slot * 8);
      }
#pragma unroll
      for (int ni = 0; ni < 4; ++ni) {
        const int row = wn + ni * 16 + l15;
        const int slot = (k0 * 4 + l4) ^ (row & 7);
        bv[ni] = *reinterpret_cast<const bf8*>(lB + row * 64 + slot * 8);
      }
      __builtin_amdgcn_s_setprio(1);
#pragma unroll
      for (int mi = 0; mi < 2; ++mi)
#pragma unroll
        for (int ni = 0; ni < 4; ++ni)
          acc[mi][ni] = mfma_bf16(af[mi], bv[ni], acc[mi][ni]);
      __builtin_amdgcn_s_setprio(0);
    }
    asm volatile("s_waitcnt vmcnt(0)" ::: "memory");
    __builtin_amdgcn_s_barrier();
    cur ^= 1;
  }

#pragma unroll
  for (int ni = 0; ni < 4; ++ni) {
    const int col = bn * 128 + wn + ni * 16 + l15;
    const float bc = bias[col];
#pragma unroll
    for (int mi = 0; mi < 2; ++mi) {
      const int row0 = bm * 64 + wm + mi * 16 + l4 * 4;
      f32x4 v = acc[mi][ni];
#pragma unroll
      for (int r = 0; r < 4; ++r)
        Cf[(size_t)(row0 + r) * N + col] = v[r] + bc;
    }
  }
}

// ---------------- fused attention: block = (b,h,z,128 q-rows), 4 waves x 32 rows ----------
// Fixed-reference exp2 softmax; per-lane l partials reduced in epilogue.
// 2-phase K/V dbuf; QK hoisted for both th; setprio on MFMA clusters.
__global__ __launch_bounds__(256, 3) void attn_kernel(
    const ushort_t* __restrict__ Q, const ushort_t* __restrict__ Kb,
    const ushort_t* __restrict__ Vt, const ushort_t* __restrict__ VMh,
    const unsigned int* __restrict__ comb_main, const unsigned int* __restrict__ comb_ng,
    ushort_t* __restrict__ AT) {
  __shared__ unsigned char kbuf[2][8192];
  __shared__ unsigned char vbuf[2][8192];
  __shared__ ushort_t vmt16[4][1088];      // per wave [32 t][34] bf16
  __shared__ unsigned int pbl[4][576];     // per wave [16 t][36 dw]

  const int tid = threadIdx.x;
  const int lane = tid & 63, wid = tid >> 6;
  const int l15 = lane & 15, l4 = lane >> 4;

  const int n = blockIdx.x;
  const int xcd = n & 7;
  const int b = xcd >> 1;
  const int idx = (xcd & 1) * 96 + (n >> 3);
  const int h = idx / 12;
  const int rem = idx - h * 12;
  const int z = rem >> 2;
  const int blk = rem & 3;
  const int g = (z == 0) ? 0 : z - 1;
  const int bh = b * NH + h;
  const int t0 = blk * 128 + wid * 32;
  const int qrow0 = (z == 0) ? t0 : TSEQ + g * TSEQ + t0;
  const int nsb = (z == 0) ? 8 : 16;

  {
    const ushort_t* src = VMh + ((size_t)bh * TGT + qrow0) * NBN;
    ushort_t* dst = vmt16[wid];
#pragma unroll
    for (int half = 0; half < 2; ++half) {
      const u16x8v v = *reinterpret_cast<const u16x8v*>(src + half * 512 + lane * 8);
      const int r = half * 16 + (lane >> 2);
      const int c0 = (lane & 3) * 8;
#pragma unroll
      for (int i = 0; i < 8; ++i) dst[r * 34 + c0 + i] = v[i];
    }
  }

  bf8 qf[2][2];
#pragma unroll
  for (int th = 0; th < 2; ++th)
#pragma unroll
    for (int hf = 0; hf < 2; ++hf)
      qf[th][hf] = *reinterpret_cast<const bf8*>(
          &Q[((size_t)bh * TGT + qrow0 + th * 16 + l15) * HD + hf * 32 + l4 * 8]);

  const unsigned int* cb[2];
  {
    const unsigned int* cbase = (z == 0)
        ? comb_main + (size_t)b * TSEQ * TSEQ
        : comb_ng + (size_t)(b * 2 + g) * TSEQ * (2 * TSEQ);
    const int sstr = (z == 0) ? TSEQ : 2 * TSEQ;
    cb[0] = cbase + (size_t)(t0 + l15) * sstr;
    cb[1] = cbase + (size_t)(t0 + 16 + l15) * sstr;
  }

  float l_run[2] = {0.f, 0.f};
  f32x4 oacc[2][4] = {};

  const int r8 = lane >> 3;
  const int swzs = ((lane & 7) ^ r8) << 4;
  const int swzr = (l15 & 7) << 4;

  auto stage = [&](int sb, int bf) {
    const int srow0 = (sb < 8) ? sb * 64 : TSEQ + g * TSEQ + (sb - 8) * 64;
    const ushort_t* ks = Kb + ((size_t)bh * TGT + srow0 + wid * 16 + r8) * HD + (swzs >> 1);
    gload16(ks, &kbuf[bf][wid * 2048 + lane * 16]);
    gload16(ks + 8 * HD, &kbuf[bf][wid * 2048 + 1024 + lane * 16]);
    const ushort_t* vs = Vt + ((size_t)bh * HD + wid * 16 + r8) * TGT + srow0 + (swzs >> 1);
    gload16(vs, &vbuf[bf][wid * 2048 + lane * 16]);
    gload16(vs + 8 * TGT, &vbuf[bf][wid * 2048 + 1024 + lane * 16]);
  };

  stage(0, 0);
  asm volatile("s_waitcnt vmcnt(0)" ::: "memory");
  __builtin_amdgcn_s_barrier();

  int cur = 0;
  for (int sb = 0; sb < nsb; ++sb) {
    const int scol = sb * 64;
    if (sb + 1 < nsb) stage(sb + 1, cur ^ 1);

    const unsigned char* kb = kbuf[cur];
    const unsigned char* vbb = vbuf[cur];

    uint4 cw[2][4];
#pragma unroll
    for (int th = 0; th < 2; ++th) {
      const unsigned int* cwp = cb[th] + scol + l4 * 4;
      cw[th][0] = *reinterpret_cast<const uint4*>(cwp);
      cw[th][1] = *reinterpret_cast<const uint4*>(cwp + 16);
      cw[th][2] = *reinterpret_cast<const uint4*>(cwp + 32);
      cw[th][3] = *reinterpret_cast<const uint4*>(cwp + 48);
    }

    bf8 kf[4][2];
#pragma unroll
    for (int j = 0; j < 4; ++j) {
      const int row = j * 16 + l15;
      kf[j][0] = *reinterpret_cast<const bf8*>(kb + row * 128 + ((l4 * 16) ^ swzr));
      kf[j][1] = *reinterpret_cast<const bf8*>(kb + row * 128 + ((64 + l4 * 16) ^ swzr));
    }
    f32x4 st[2][4];
    __builtin_amdgcn_s_setprio(1);
#pragma unroll
    for (int th = 0; th < 2; ++th)
#pragma unroll
      for (int j = 0; j < 4; ++j) {
        f32x4 s4 = {};
        s4 = mfma_bf16(kf[j][0], qf[th][0], s4);
        s4 = mfma_bf16(kf[j][1], qf[th][1], s4);
        st[th][j] = s4;
      }
    __builtin_amdgcn_s_setprio(0);

#pragma unroll
    for (int th = 0; th < 2; ++th) {
      const ushort_t* vrow = vmt16[wid] + (th * 16 + l15) * 34;
      unsigned int pk[4][2];
      float lsum = 0.f;
#pragma unroll
      for (int j = 0; j < 4; ++j) {
        const unsigned int w0 = cw[th][j].x, w1 = cw[th][j].y;
        const unsigned int w2 = cw[th][j].z, w3 = cw[th][j].w;
        const float p0 = exp2f(st[th][j][0] + __builtin_bit_cast(float, w0 & 0xffff0000u) + bf2f(vrow[w0 & 31u]));
        const float p1 = exp2f(st[th][j][1] + __builtin_bit_cast(float, w1 & 0xffff0000u) + bf2f(vrow[w1 & 31u]));
        const float p2 = exp2f(st[th][j][2] + __builtin_bit_cast(float, w2 & 0xffff0000u) + bf2f(vrow[w2 & 31u]));
        const float p3 = exp2f(st[th][j][3] + __builtin_bit_cast(float, w3 & 0xffff0000u) + bf2f(vrow[w3 & 31u]));
        lsum += (p0 + p1) + (p2 + p3);
        pk[j][0] = packbf(p0, p1);
        pk[j][1] = packbf(p2, p3);
      }
      l_run[th] += lsum;

      {
        unsigned int* prow = &pbl[wid][l15 * 36];
#pragma unroll
        for (int j = 0; j < 4; ++j) {
          uint2 w2v;
          w2v.x = pk[j][0];
          w2v.y = pk[j][1];
          *reinterpret_cast<uint2*>(&prow[j * 8 + l4 * 2]) = w2v;
        }
      }
      const unsigned char* pbase = reinterpret_cast<const unsigned char*>(&pbl[wid][0]);
#pragma unroll
      for (int k32 = 0; k32 < 2; ++k32) {
        const bf8 pa = *reinterpret_cast<const bf8*>(
            pbase + l15 * 144 + k32 * 64 + l4 * 16);
        __builtin_amdgcn_s_setprio(1);
#pragma unroll
        for (int dt = 0; dt < 4; ++dt) {
          const bf8 vb = *reinterpret_cast<const bf8*>(
              vbb + (dt * 16 + l15) * 128 + ((k32 * 64 + l4 * 16) ^ swzr));
          oacc[th][dt] = mfma_bf16(pa, vb, oacc[th][dt]);
        }
        __builtin_amdgcn_s_setprio(0);
      }
    }

    asm volatile("s_waitcnt vmcnt(0)" ::: "memory");
    __builtin_amdgcn_s_barrier();
    cur ^= 1;
  }

  // ---- epilogue: deferred cross-lane l reduction, then divide + store
#pragma unroll
  for (int th = 0; th < 2; ++th) {
    float lt = l_run[th];
    lt += __shfl_xor(lt, 16);
    lt += __shfl_xor(lt, 32);
    const float linv = 1.f / lt;
    f32x4 bs;
    bs[0] = lanebcast(linv, l4 * 4 + 0);
    bs[1] = lanebcast(linv, l4 * 4 + 1);
    bs[2] = lanebcast(linv, l4 * 4 + 2);
    bs[3] = lanebcast(linv, l4 * 4 + 3);
#pragma unroll
    for (int dt = 0; dt < 4; ++dt) {
#pragma unroll
      for (int r = 0; r < 4; ++r) {
        const int tout = qrow0 + th * 16 + l4 * 4 + r;
        AT[((size_t)tout * BSZN + b) * EMB + h * HD + dt * 16 + l15] =
            f2bf(oacc[th][dt][r] * bs[r]);
      }
    }
  }
}

extern "C" void kernel_launch(void* const* d_in, const int* in_sizes, int n_in,
                              void* d_out, int out_size, void* d_ws, size_t ws_size,
                              hipStream_t stream) {
  const float* query     = (const float*)d_in[0];
  const float* mask_main = (const float*)d_in[1];
  const float* mask_ng   = (const float*)d_in[2];
  const int*   ib_main   = (const int*)d_in[3];
  const int*   ib_rel    = (const int*)d_in[4];
  const float* w_in      = (const float*)d_in[5];
  const float* b_in      = (const float*)d_in[6];
  const float* w_out     = (const float*)d_in[7];
  const float* b_out     = (const float*)d_in[8];
  const float* w_rel     = (const float*)d_in[9];
  const float* b_rel     = (const float*)d_in[10];
  float* out = (float*)d_out;

  ushort_t* qbf    = (ushort_t*)d_ws;            // 6291456
  ushort_t* winbf  = qbf + 6291456;              // 3145728
  ushort_t* woutbf = winbf + 3145728;            // 1048576
  ushort_t* relwbf = woutbf + 1048576;           // 524288
  ushort_t* Qb     = relwbf + 524288;            // 6291456
  ushort_t* Kbuf   = Qb + 6291456;               // 6291456
  ushort_t* Vtb    = Kbuf + 6291456;             // 6291456
  ushort_t* VMh    = Vtb + 6291456;              // 3145728
  unsigned int* comb_main = (unsigned int*)(VMh + 3145728);  // 1048576 u32
  unsigned int* comb_ng   = comb_main + 1048576;             // 4194304 u32
  ushort_t* AT     = qbf;                        // alias

  // fused prep: cvt + comb (mask pre-scaled by log2e)
  {
    const int total = 2752512 + 262144 + 1048576;
    prep_all_kernel<<<(total + 255) / 256, 256, 0, stream>>>(
        query, w_in, w_out, w_rel, ib_main, ib_rel, mask_main, mask_ng,
        qbf, winbf, woutbf, relwbf, comb_main, comb_ng);
  }

  // fused in-projection + rel-value table (XCD-confined, BK=64 dbuf)
  gemm_in<<<1344, 256, 0, stream>>>(qbf, winbf, b_in,
                                    Qb, Kbuf, Vtb, relwbf, b_rel, VMh, 1024);
  // fused attention
  attn_kernel<<<768, 256, 0, stream>>>(Qb, Kbuf, Vtb, VMh, comb_main, comb_ng, AT);
  // out-projection (BM=64, 768 blocks, 48KB dbuf -> 3 blocks/CU)
  gemm_out<<<768, 256, 0, stream>>>(AT, woutbf, b_out, out);
}